// Round 2
// baseline (247.741 us; speedup 1.0000x reference)
//
#include <hip/hip_runtime.h>

// RoIAlign: features (2,256,200,304) fp32 NCHW, rois (512,5) fp32,
// out (512,256,7,7) fp32. OUT=7x7, sampling ratio G=2, scale 0.25.
//
// Round 9: gather rewritten with separable corner dedup. The 2x2-sample
// bilinear average per bin is separable: sum_s wy(s)wx(s)V[yc,xc] =
// (merged y-corner weights) x (merged x-corner weights). Per (roi,ph):
// y-corners 4 -> ny unique rows (typ. 2-3, shared across all 7 bins);
// per-bin x-corners 4 -> nx unique cols (typ. 3). Loads drop 112 ->
// ny*sum(nx) ~ 63 per thread (~205 MB -> ~117 MB read traffic), FMAs
// nearly halve. Loop bounds are wave-uniform (LDS), acc indexing static.
// Transpose = round-8 (512-B bursts, at HBM floor), unchanged for
// attribution.

#define OUT_H 7
#define OUT_W 7
constexpr float SPATIAL_SCALE = 0.25f;
constexpr int CN = 256;   // channels
constexpr int FH = 200;
constexpr int FW = 304;
constexpr int N_IMG = 2;
constexpr int N_ROIS = 512;
constexpr int PIX = FH * FW;               // 60800 = 475 * 128
constexpr size_t PLANE = (size_t)PIX;
constexpr size_t NHWC_ELEMS = (size_t)N_IMG * PLANE * CN;
constexpr size_t NHWC_BF16_BYTES = NHWC_ELEMS * sizeof(unsigned short);

constexpr int CT = 64;    // channel tile
constexpr int PT = 128;   // pixel tile (60800 % 128 == 0)

__device__ __forceinline__ unsigned short f2bf_rne(float f) {
    unsigned int u = __float_as_uint(f);
    unsigned int r = (u + 0x7FFFu + ((u >> 16) & 1u)) >> 16;  // RNE
    return (unsigned short)r;
}

// ---------------- tiled transpose NCHW fp32 -> NHWC bf16 ----------------
// grid (PIX/PT = 475, N_IMG*CN/CT = 8), 256 threads.
// Phase 1: thread (q = t&31, r = t>>5) loads float4 of channel c = r + 8i
//   at pixel offset 4q. Per wave instruction (fixed i): 2 x 512-B bursts.
// Phase 2: thread (cq = t&7, p0 = t>>3) packs 8 channels -> uint4 at
//   pixel p = p0 + 32*i2; full-128B-line NHWC writes. Row stride 129
//   keeps phase-2 LDS reads at 2 lanes/bank (free).
__global__ __launch_bounds__(256) void nchw_to_nhwc_bf16_tiled(
    const float* __restrict__ in, unsigned short* __restrict__ ws)
{
    const int pbase = blockIdx.x * PT;
    const int nc = blockIdx.y;           // 0..7
    const int n = nc >> 2;
    const int cbase = (nc & 3) * CT;

    __shared__ float tile[CT][PT + 1];   // 64 x 129 fp32 = 33,024 B

    {
        const int q = threadIdx.x & 31;  // float4 slot within pixel row
        const int r = threadIdx.x >> 5;  // 0..7
        const float* src = in + ((size_t)n * CN + cbase) * PLANE + pbase + 4 * q;
#pragma unroll
        for (int i = 0; i < 8; ++i) {
            const int c = r + 8 * i;
            const float4 v = *(const float4*)(src + (size_t)c * PLANE);
            tile[c][4 * q + 0] = v.x;
            tile[c][4 * q + 1] = v.y;
            tile[c][4 * q + 2] = v.z;
            tile[c][4 * q + 3] = v.w;
        }
    }
    __syncthreads();
    {
        const int cq = threadIdx.x & 7;  // channel octet: channels 8cq..8cq+7
        const int p0 = threadIdx.x >> 3; // 0..31
        unsigned short* dstbase =
            ws + ((size_t)n * PLANE + pbase) * CN + cbase + 8 * cq;
#pragma unroll
        for (int i2 = 0; i2 < 4; ++i2) {
            const int p = p0 + 32 * i2;
            uint4 pk;
            pk.x = (unsigned int)f2bf_rne(tile[8 * cq + 0][p]) |
                   ((unsigned int)f2bf_rne(tile[8 * cq + 1][p]) << 16);
            pk.y = (unsigned int)f2bf_rne(tile[8 * cq + 2][p]) |
                   ((unsigned int)f2bf_rne(tile[8 * cq + 3][p]) << 16);
            pk.z = (unsigned int)f2bf_rne(tile[8 * cq + 4][p]) |
                   ((unsigned int)f2bf_rne(tile[8 * cq + 5][p]) << 16);
            pk.w = (unsigned int)f2bf_rne(tile[8 * cq + 6][p]) |
                   ((unsigned int)f2bf_rne(tile[8 * cq + 7][p]) << 16);
            *(uint4*)(dstbase + (size_t)p * CN) = pk;
        }
    }
}

// ---------------- gather on NHWC bf16: (roi, ph) blocks, XCD-swizzled ----
// 1-D grid of 3584; decode so all 7 ph of a roi share (id % 8) => same XCD.
// Separable dedup: unique y-corner rows (<=4, shared by all bins of the ph
// row) x per-bin unique x-corner cols (<=4). Weights merged additively.
__global__ __launch_bounds__(128) void roi_align_nhwc_bf16(
    const unsigned short* __restrict__ ws,
    const float* __restrict__ rois,
    float* __restrict__ out)
{
    const int b = blockIdx.x;
    const int x = b & 7;                 // XCD residue
    const int s_id = b >> 3;             // 0..447
    const int r  = (s_id / 7) * 8 + x;   // roi
    const int ph = s_id % 7;             // output row
    const int t  = threadIdx.x;          // channel pair: 2t, 2t+1

    __shared__ float s_roi[5];
    __shared__ int   s_ny;
    __shared__ int   s_yoff[4];          // byte offsets: row*FW*CN*2
    __shared__ float s_wy[4];
    __shared__ int   s_nx[OUT_W];
    __shared__ int   s_xoff[OUT_W][4];   // byte offsets: col*CN*2
    __shared__ float s_wx[OUT_W][4];
    __shared__ int   s_b;

    if (t < 5) s_roi[t] = rois[r * 5 + t];
    __syncthreads();

    if (t < 8) {
        const float x1 = s_roi[1] * SPATIAL_SCALE - 0.5f;
        const float y1 = s_roi[2] * SPATIAL_SCALE - 0.5f;
        const float x2 = s_roi[3] * SPATIAL_SCALE - 0.5f;
        const float y2 = s_roi[4] * SPATIAL_SCALE - 0.5f;
        const float bin_w = (x2 - x1) / OUT_W;
        const float bin_h = (y2 - y1) / OUT_H;
        if (t == 0) {
            // ---- y side: 2 samples x 2 corners -> merged unique rows ----
            int   col[4];
            float w[4];
#pragma unroll
            for (int gy = 0; gy < 2; ++gy) {
                const float y = y1 + ph * bin_h + (gy + 0.5f) * bin_h * 0.5f;
                const float vy = (y > -1.0f && y < (float)FH) ? 1.0f : 0.0f;
                const float yc = fminf(fmaxf(y, 0.0f), (float)(FH - 1));
                const int y0 = (int)floorf(yc);
                const int y1i = min(y0 + 1, FH - 1);
                const float ly = yc - (float)y0;
                col[2 * gy + 0] = y0;  w[2 * gy + 0] = (1.0f - ly) * vy;
                col[2 * gy + 1] = y1i; w[2 * gy + 1] = ly * vy;
            }
            int   mcol[4];
            float mw[4];
            int n = 0;
#pragma unroll
            for (int k = 0; k < 4; ++k) {
                if (w[k] == 0.0f) continue;
                bool found = false;
                for (int j = 0; j < n; ++j) {
                    if (mcol[j] == col[k]) { mw[j] += w[k]; found = true; break; }
                }
                if (!found) { mcol[n] = col[k]; mw[n] = w[k]; ++n; }
            }
            for (int j = 0; j < n; ++j) {
                s_yoff[j] = mcol[j] * (FW * CN * 2);
                s_wy[j]   = mw[j];
            }
            s_ny = n;
            s_b = (int)s_roi[0];
        } else {
            // ---- x side for bin pw = t-1 ----
            const int pw = t - 1;
            int   col[4];
            float w[4];
#pragma unroll
            for (int gx = 0; gx < 2; ++gx) {
                const float xf = x1 + pw * bin_w + (gx + 0.5f) * bin_w * 0.5f;
                const float vx = (xf > -1.0f && xf < (float)FW) ? 1.0f : 0.0f;
                const float xc = fminf(fmaxf(xf, 0.0f), (float)(FW - 1));
                const int x0 = (int)floorf(xc);
                const int x1i = min(x0 + 1, FW - 1);
                const float lx = xc - (float)x0;
                col[2 * gx + 0] = x0;  w[2 * gx + 0] = (1.0f - lx) * vx;
                col[2 * gx + 1] = x1i; w[2 * gx + 1] = lx * vx;
            }
            int   mcol[4];
            float mw[4];
            int n = 0;
#pragma unroll
            for (int k = 0; k < 4; ++k) {
                if (w[k] == 0.0f) continue;
                bool found = false;
                for (int j = 0; j < n; ++j) {
                    if (mcol[j] == col[k]) { mw[j] += w[k]; found = true; break; }
                }
                if (!found) { mcol[n] = col[k]; mw[n] = w[k]; ++n; }
            }
            for (int j = 0; j < n; ++j) {
                s_xoff[pw][j] = mcol[j] * (CN * 2);
                s_wx[pw][j]   = mw[j];
            }
            s_nx[pw] = n;
        }
    }
    __syncthreads();

    const char* base = (const char*)(ws + (size_t)s_b * (PLANE * CN)) + 4 * t;

    float acc0[OUT_W] = {0.f, 0.f, 0.f, 0.f, 0.f, 0.f, 0.f};
    float acc1[OUT_W] = {0.f, 0.f, 0.f, 0.f, 0.f, 0.f, 0.f};

    const int ny = s_ny;
    for (int yi = 0; yi < ny; ++yi) {
        const float wy = s_wy[yi];
        const char* rb = base + s_yoff[yi];
#pragma unroll
        for (int pw = 0; pw < OUT_W; ++pw) {
            float t0 = 0.f, t1 = 0.f;
            const int nx = s_nx[pw];
            for (int j = 0; j < nx; ++j) {
                const unsigned int u = *(const unsigned int*)(rb + s_xoff[pw][j]);
                const float wx = s_wx[pw][j];
                t0 = fmaf(wx, __uint_as_float(u << 16), t0);
                t1 = fmaf(wx, __uint_as_float(u & 0xFFFF0000u), t1);
            }
            acc0[pw] = fmaf(wy, t0, acc0[pw]);
            acc1[pw] = fmaf(wy, t1, acc1[pw]);
        }
    }

    const size_t outbase = ((size_t)r * CN + 2 * t) * (OUT_H * OUT_W) + (size_t)ph * OUT_W;
#pragma unroll
    for (int pw = 0; pw < OUT_W; ++pw) {
        out[outbase + pw] = acc0[pw] * 0.25f;
        out[outbase + (OUT_H * OUT_W) + pw] = acc1[pw] * 0.25f;
    }
}

// ---------------- fallback: NCHW gather (round-1 kernel) ----------------
__global__ __launch_bounds__(256) void roi_align_nchw(
    const float* __restrict__ feat,
    const float* __restrict__ rois,
    float* __restrict__ out)
{
    const int r  = blockIdx.x;
    const int ph = blockIdx.y;
    const int c  = threadIdx.x;

    __shared__ float s_roi[5];
    __shared__ int   s_off[28][4];
    __shared__ float s_w[28][4];
    __shared__ int   s_b;

    if (threadIdx.x < 5) s_roi[threadIdx.x] = rois[r * 5 + threadIdx.x];
    __syncthreads();

    if (threadIdx.x < 28) {
        const int s  = threadIdx.x;
        const int gy = s / 14;
        const int ix = s % 14;
        const float x1 = s_roi[1] * SPATIAL_SCALE - 0.5f;
        const float y1 = s_roi[2] * SPATIAL_SCALE - 0.5f;
        const float x2 = s_roi[3] * SPATIAL_SCALE - 0.5f;
        const float y2 = s_roi[4] * SPATIAL_SCALE - 0.5f;
        const float bin_w = (x2 - x1) / OUT_W;
        const float bin_h = (y2 - y1) / OUT_H;
        const float y = y1 + ph * bin_h + (gy + 0.5f) * bin_h * 0.5f;
        const float xf = x1 + (ix >> 1) * bin_w + ((ix & 1) + 0.5f) * bin_w * 0.5f;
        const float validf =
            (y > -1.0f && y < (float)FH && xf > -1.0f && xf < (float)FW) ? 1.0f : 0.0f;
        const float yc = fminf(fmaxf(y, 0.0f), (float)(FH - 1));
        const float xc = fminf(fmaxf(xf, 0.0f), (float)(FW - 1));
        const int y0 = (int)floorf(yc);
        const int x0 = (int)floorf(xc);
        const int y1i = min(y0 + 1, FH - 1);
        const int x1i = min(x0 + 1, FW - 1);
        const float ly = yc - (float)y0;
        const float lx = xc - (float)x0;
        const float hy = 1.0f - ly;
        const float hx = 1.0f - lx;
        s_off[s][0] = y0  * FW + x0;
        s_off[s][1] = y0  * FW + x1i;
        s_off[s][2] = y1i * FW + x0;
        s_off[s][3] = y1i * FW + x1i;
        s_w[s][0] = hy * hx * validf;
        s_w[s][1] = hy * lx * validf;
        s_w[s][2] = ly * hx * validf;
        s_w[s][3] = ly * lx * validf;
    }
    if (threadIdx.x == 0) s_b = (int)s_roi[0];
    __syncthreads();

    const float* base = feat + ((size_t)s_b * CN + c) * PLANE;

    float acc[OUT_W] = {0.f, 0.f, 0.f, 0.f, 0.f, 0.f, 0.f};
#pragma unroll
    for (int s = 0; s < 28; ++s) {
        const float v0 = base[s_off[s][0]];
        const float v1 = base[s_off[s][1]];
        const float v2 = base[s_off[s][2]];
        const float v3 = base[s_off[s][3]];
        acc[(s % 14) >> 1] += s_w[s][0] * v0 + s_w[s][1] * v1 +
                              s_w[s][2] * v2 + s_w[s][3] * v3;
    }

    const size_t outbase = ((size_t)r * CN + c) * (OUT_H * OUT_W) + (size_t)ph * OUT_W;
#pragma unroll
    for (int pw = 0; pw < OUT_W; ++pw) {
        out[outbase + pw] = acc[pw] * 0.25f;
    }
}

extern "C" void kernel_launch(void* const* d_in, const int* in_sizes, int n_in,
                              void* d_out, int out_size, void* d_ws, size_t ws_size,
                              hipStream_t stream) {
    const float* feat = (const float*)d_in[0];
    const float* rois = (const float*)d_in[1];
    float* out = (float*)d_out;

    if (ws_size >= NHWC_BF16_BYTES) {
        unsigned short* ws = (unsigned short*)d_ws;
        dim3 tgrid(PIX / PT, (N_IMG * CN) / CT, 1);  // 475 x 8 = 3800 blocks
        nchw_to_nhwc_bf16_tiled<<<tgrid, dim3(256, 1, 1), 0, stream>>>(feat, ws);
        roi_align_nhwc_bf16<<<dim3(N_ROIS * OUT_H, 1, 1), dim3(128, 1, 1), 0, stream>>>(
            ws, rois, out);
    } else {
        dim3 grid(N_ROIS, OUT_H, 1);
        roi_align_nchw<<<grid, dim3(256, 1, 1), 0, stream>>>(feat, rois, out);
    }
}

// Round 3
// 234.585 us; speedup vs baseline: 1.0561x; 1.0561x over previous
//
#include <hip/hip_runtime.h>

// RoIAlign: features (2,256,200,304) fp32 NCHW, rois (512,5) fp32,
// out (512,256,7,7) fp32. OUT=7x7, sampling ratio G=2, scale 0.25.
//
// Round 10: revert gather to round-8 structure (compile-time bounds, fully
// unrolled loads -- round-9's runtime-bound dedup collapsed MLP, +29us;
// duplicate-corner loads were already L1-absorbed so dedup saved no L3
// bytes). New: split each (roi,ph) block by output-column half: block A =
// pw 0-3 (16 samples/64 loads), block B = pw 4-6 (12 samples/48 loads).
// 7168 blocks, disjoint outputs, bounds still compile-time, same XCD
// swizzle (14 blocks/roi share XCD). Probes latency- vs BW-bound gather.
// Transpose = round-8 (512-B bursts, at HBM floor), unchanged.

#define OUT_H 7
#define OUT_W 7
constexpr float SPATIAL_SCALE = 0.25f;
constexpr int CN = 256;   // channels
constexpr int FH = 200;
constexpr int FW = 304;
constexpr int N_IMG = 2;
constexpr int N_ROIS = 512;
constexpr int PIX = FH * FW;               // 60800 = 475 * 128
constexpr size_t PLANE = (size_t)PIX;
constexpr size_t NHWC_ELEMS = (size_t)N_IMG * PLANE * CN;
constexpr size_t NHWC_BF16_BYTES = NHWC_ELEMS * sizeof(unsigned short);

constexpr int CT = 64;    // channel tile
constexpr int PT = 128;   // pixel tile (60800 % 128 == 0)

__device__ __forceinline__ unsigned short f2bf_rne(float f) {
    unsigned int u = __float_as_uint(f);
    unsigned int r = (u + 0x7FFFu + ((u >> 16) & 1u)) >> 16;  // RNE
    return (unsigned short)r;
}

// ---------------- tiled transpose NCHW fp32 -> NHWC bf16 ----------------
// grid (PIX/PT = 475, N_IMG*CN/CT = 8), 256 threads.
// Phase 1: thread (q = t&31, r = t>>5) loads float4 of channel c = r + 8i
//   at pixel offset 4q. Per wave instruction (fixed i): 2 x 512-B bursts.
// Phase 2: thread (cq = t&7, p0 = t>>3) packs 8 channels -> uint4 at
//   pixel p = p0 + 32*i2; full-128B-line NHWC writes. Row stride 129
//   keeps phase-2 LDS reads at 2 lanes/bank (free).
__global__ __launch_bounds__(256) void nchw_to_nhwc_bf16_tiled(
    const float* __restrict__ in, unsigned short* __restrict__ ws)
{
    const int pbase = blockIdx.x * PT;
    const int nc = blockIdx.y;           // 0..7
    const int n = nc >> 2;
    const int cbase = (nc & 3) * CT;

    __shared__ float tile[CT][PT + 1];   // 64 x 129 fp32 = 33,024 B

    {
        const int q = threadIdx.x & 31;  // float4 slot within pixel row
        const int r = threadIdx.x >> 5;  // 0..7
        const float* src = in + ((size_t)n * CN + cbase) * PLANE + pbase + 4 * q;
#pragma unroll
        for (int i = 0; i < 8; ++i) {
            const int c = r + 8 * i;
            const float4 v = *(const float4*)(src + (size_t)c * PLANE);
            tile[c][4 * q + 0] = v.x;
            tile[c][4 * q + 1] = v.y;
            tile[c][4 * q + 2] = v.z;
            tile[c][4 * q + 3] = v.w;
        }
    }
    __syncthreads();
    {
        const int cq = threadIdx.x & 7;  // channel octet: channels 8cq..8cq+7
        const int p0 = threadIdx.x >> 3; // 0..31
        unsigned short* dstbase =
            ws + ((size_t)n * PLANE + pbase) * CN + cbase + 8 * cq;
#pragma unroll
        for (int i2 = 0; i2 < 4; ++i2) {
            const int p = p0 + 32 * i2;
            uint4 pk;
            pk.x = (unsigned int)f2bf_rne(tile[8 * cq + 0][p]) |
                   ((unsigned int)f2bf_rne(tile[8 * cq + 1][p]) << 16);
            pk.y = (unsigned int)f2bf_rne(tile[8 * cq + 2][p]) |
                   ((unsigned int)f2bf_rne(tile[8 * cq + 3][p]) << 16);
            pk.z = (unsigned int)f2bf_rne(tile[8 * cq + 4][p]) |
                   ((unsigned int)f2bf_rne(tile[8 * cq + 5][p]) << 16);
            pk.w = (unsigned int)f2bf_rne(tile[8 * cq + 6][p]) |
                   ((unsigned int)f2bf_rne(tile[8 * cq + 7][p]) << 16);
            *(uint4*)(dstbase + (size_t)p * CN) = pk;
        }
    }
}

// ---------------- gather on NHWC bf16: (roi, ph, half) blocks ------------
// 1-D grid of 7168; decode so all 14 blocks of a roi share (id % 8) =>
// same XCD. half=0: samples ix 0-7 -> pw 0-3 (16 samples, 64 loads);
// half=1: samples ix 8-13 -> pw 4-6 (12 samples, 48 loads). All loop
// bounds compile-time; loads fully unrolled (round-9 lesson: MLP rules).
__global__ __launch_bounds__(128) void roi_align_nhwc_bf16(
    const unsigned short* __restrict__ ws,
    const float* __restrict__ rois,
    float* __restrict__ out)
{
    const int b = blockIdx.x;
    const int x = b & 7;                 // XCD residue
    const int sid = b >> 3;              // 0..895
    const int half = sid & 1;
    const int ph = (sid >> 1) % 7;       // output row
    const int r  = ((sid >> 1) / 7) * 8 + x;  // roi
    const int t  = threadIdx.x;          // channel pair: 2t, 2t+1

    __shared__ float s_roi[5];
    __shared__ int   s_off[16][4];       // BYTE offsets into NHWC bf16 image
    __shared__ float s_w[16][4];
    __shared__ int   s_b;

    if (t < 5) s_roi[t] = rois[r * 5 + t];
    __syncthreads();

    const int NW = half ? 6 : 8;         // samples per gy row in this half
    const int NS = 2 * NW;               // total samples in this half
    if (t < NS) {
        const int gy  = (t >= NW) ? 1 : 0;
        const int ixl = t - gy * NW;
        const int ix  = half * 8 + ixl;  // global sample column 0..13
        const float x1 = s_roi[1] * SPATIAL_SCALE - 0.5f;
        const float y1 = s_roi[2] * SPATIAL_SCALE - 0.5f;
        const float x2 = s_roi[3] * SPATIAL_SCALE - 0.5f;
        const float y2 = s_roi[4] * SPATIAL_SCALE - 0.5f;
        const float bin_w = (x2 - x1) / OUT_W;
        const float bin_h = (y2 - y1) / OUT_H;
        const float y = y1 + ph * bin_h + (gy + 0.5f) * bin_h * 0.5f;
        const float xf = x1 + (ix >> 1) * bin_w + ((ix & 1) + 0.5f) * bin_w * 0.5f;
        const float validf =
            (y > -1.0f && y < (float)FH && xf > -1.0f && xf < (float)FW) ? 1.0f : 0.0f;
        const float yc = fminf(fmaxf(y, 0.0f), (float)(FH - 1));
        const float xc = fminf(fmaxf(xf, 0.0f), (float)(FW - 1));
        const int y0 = (int)floorf(yc);
        const int x0 = (int)floorf(xc);
        const int y1i = min(y0 + 1, FH - 1);
        const int x1i = min(x0 + 1, FW - 1);
        const float ly = yc - (float)y0;
        const float lx = xc - (float)x0;
        const float hy = 1.0f - ly;
        const float hx = 1.0f - lx;
        s_off[t][0] = ((y0  * FW + x0 ) * CN) * 2;
        s_off[t][1] = ((y0  * FW + x1i) * CN) * 2;
        s_off[t][2] = ((y1i * FW + x0 ) * CN) * 2;
        s_off[t][3] = ((y1i * FW + x1i) * CN) * 2;
        s_w[t][0] = hy * hx * validf;
        s_w[t][1] = hy * lx * validf;
        s_w[t][2] = ly * hx * validf;
        s_w[t][3] = ly * lx * validf;
    }
    if (t == 0) s_b = (int)s_roi[0];
    __syncthreads();

    const char* base =
        (const char*)(ws + (size_t)s_b * (PLANE * CN) + 2 * t);

    float acc0[4] = {0.f, 0.f, 0.f, 0.f};
    float acc1[4] = {0.f, 0.f, 0.f, 0.f};

    if (half == 0) {
#pragma unroll
        for (int s = 0; s < 16; ++s) {
            const int pw = (s & 7) >> 1;     // local pw 0..3
#pragma unroll
            for (int k = 0; k < 4; ++k) {
                const unsigned int u = *(const unsigned int*)(base + s_off[s][k]);
                const float f0 = __uint_as_float(u << 16);
                const float f1 = __uint_as_float(u & 0xFFFF0000u);
                const float w = s_w[s][k];
                acc0[pw] = fmaf(w, f0, acc0[pw]);
                acc1[pw] = fmaf(w, f1, acc1[pw]);
            }
        }
    } else {
#pragma unroll
        for (int s = 0; s < 12; ++s) {
            const int pw = (s % 6) >> 1;     // local pw 0..2
#pragma unroll
            for (int k = 0; k < 4; ++k) {
                const unsigned int u = *(const unsigned int*)(base + s_off[s][k]);
                const float f0 = __uint_as_float(u << 16);
                const float f1 = __uint_as_float(u & 0xFFFF0000u);
                const float w = s_w[s][k];
                acc0[pw] = fmaf(w, f0, acc0[pw]);
                acc1[pw] = fmaf(w, f1, acc1[pw]);
            }
        }
    }

    const int pw0 = half ? 4 : 0;
    const int npw = half ? 3 : 4;
    const size_t outbase = ((size_t)r * CN + 2 * t) * (OUT_H * OUT_W)
                         + (size_t)ph * OUT_W + pw0;
    for (int pw = 0; pw < npw; ++pw) {
        out[outbase + pw] = acc0[pw] * 0.25f;
        out[outbase + (OUT_H * OUT_W) + pw] = acc1[pw] * 0.25f;
    }
}

// ---------------- fallback: NCHW gather (round-1 kernel) ----------------
__global__ __launch_bounds__(256) void roi_align_nchw(
    const float* __restrict__ feat,
    const float* __restrict__ rois,
    float* __restrict__ out)
{
    const int r  = blockIdx.x;
    const int ph = blockIdx.y;
    const int c  = threadIdx.x;

    __shared__ float s_roi[5];
    __shared__ int   s_off[28][4];
    __shared__ float s_w[28][4];
    __shared__ int   s_b;

    if (threadIdx.x < 5) s_roi[threadIdx.x] = rois[r * 5 + threadIdx.x];
    __syncthreads();

    if (threadIdx.x < 28) {
        const int s  = threadIdx.x;
        const int gy = s / 14;
        const int ix = s % 14;
        const float x1 = s_roi[1] * SPATIAL_SCALE - 0.5f;
        const float y1 = s_roi[2] * SPATIAL_SCALE - 0.5f;
        const float x2 = s_roi[3] * SPATIAL_SCALE - 0.5f;
        const float y2 = s_roi[4] * SPATIAL_SCALE - 0.5f;
        const float bin_w = (x2 - x1) / OUT_W;
        const float bin_h = (y2 - y1) / OUT_H;
        const float y = y1 + ph * bin_h + (gy + 0.5f) * bin_h * 0.5f;
        const float xf = x1 + (ix >> 1) * bin_w + ((ix & 1) + 0.5f) * bin_w * 0.5f;
        const float validf =
            (y > -1.0f && y < (float)FH && xf > -1.0f && xf < (float)FW) ? 1.0f : 0.0f;
        const float yc = fminf(fmaxf(y, 0.0f), (float)(FH - 1));
        const float xc = fminf(fmaxf(xf, 0.0f), (float)(FW - 1));
        const int y0 = (int)floorf(yc);
        const int x0 = (int)floorf(xc);
        const int y1i = min(y0 + 1, FH - 1);
        const int x1i = min(x0 + 1, FW - 1);
        const float ly = yc - (float)y0;
        const float lx = xc - (float)x0;
        const float hy = 1.0f - ly;
        const float hx = 1.0f - lx;
        s_off[s][0] = y0  * FW + x0;
        s_off[s][1] = y0  * FW + x1i;
        s_off[s][2] = y1i * FW + x0;
        s_off[s][3] = y1i * FW + x1i;
        s_w[s][0] = hy * hx * validf;
        s_w[s][1] = hy * lx * validf;
        s_w[s][2] = ly * hx * validf;
        s_w[s][3] = ly * lx * validf;
    }
    if (threadIdx.x == 0) s_b = (int)s_roi[0];
    __syncthreads();

    const float* base = feat + ((size_t)s_b * CN + c) * PLANE;

    float acc[OUT_W] = {0.f, 0.f, 0.f, 0.f, 0.f, 0.f, 0.f};
#pragma unroll
    for (int s = 0; s < 28; ++s) {
        const float v0 = base[s_off[s][0]];
        const float v1 = base[s_off[s][1]];
        const float v2 = base[s_off[s][2]];
        const float v3 = base[s_off[s][3]];
        acc[(s % 14) >> 1] += s_w[s][0] * v0 + s_w[s][1] * v1 +
                              s_w[s][2] * v2 + s_w[s][3] * v3;
    }

    const size_t outbase = ((size_t)r * CN + c) * (OUT_H * OUT_W) + (size_t)ph * OUT_W;
#pragma unroll
    for (int pw = 0; pw < OUT_W; ++pw) {
        out[outbase + pw] = acc[pw] * 0.25f;
    }
}

extern "C" void kernel_launch(void* const* d_in, const int* in_sizes, int n_in,
                              void* d_out, int out_size, void* d_ws, size_t ws_size,
                              hipStream_t stream) {
    const float* feat = (const float*)d_in[0];
    const float* rois = (const float*)d_in[1];
    float* out = (float*)d_out;

    if (ws_size >= NHWC_BF16_BYTES) {
        unsigned short* ws = (unsigned short*)d_ws;
        dim3 tgrid(PIX / PT, (N_IMG * CN) / CT, 1);  // 475 x 8 = 3800 blocks
        nchw_to_nhwc_bf16_tiled<<<tgrid, dim3(256, 1, 1), 0, stream>>>(feat, ws);
        roi_align_nhwc_bf16<<<dim3(N_ROIS * OUT_H * 2, 1, 1), dim3(128, 1, 1), 0, stream>>>(
            ws, rois, out);
    } else {
        dim3 grid(N_ROIS, OUT_H, 1);
        roi_align_nchw<<<grid, dim3(256, 1, 1), 0, stream>>>(feat, rois, out);
    }
}

// Round 4
// 220.323 us; speedup vs baseline: 1.1244x; 1.0647x over previous
//
#include <hip/hip_runtime.h>

// RoIAlign: features (2,256,200,304) fp32 NCHW, rois (512,5) fp32,
// out (512,256,7,7) fp32. OUT=7x7, sampling ratio G=2, scale 0.25.
//
// Round 11: gather restored to round-8 structure (proven 218.4us: 3584
// (roi,ph) XCD-swizzled blocks, 28x4 compile-time-unrolled corner loads,
// full MLP), re-expressed at 64 threads x uint2 (4 channels/thread): each
// corner is now ONE 512-B wave instruction instead of two 256-B ones.
// Halves load-instruction/L1-request count; bytes, MLP depth, swizzle,
// arithmetic identical. One-wave block also makes prologue barriers
// trivial. (r9 runtime-bound dedup: +29us, MLP collapse. r10 pw-split:
// +16us, doubled per-block fixed cost. Both reverted.)
// Transpose = round-8 (512-B bursts, at HBM floor), unchanged.

#define OUT_H 7
#define OUT_W 7
constexpr float SPATIAL_SCALE = 0.25f;
constexpr int CN = 256;   // channels
constexpr int FH = 200;
constexpr int FW = 304;
constexpr int N_IMG = 2;
constexpr int N_ROIS = 512;
constexpr int PIX = FH * FW;               // 60800 = 475 * 128
constexpr size_t PLANE = (size_t)PIX;
constexpr size_t NHWC_ELEMS = (size_t)N_IMG * PLANE * CN;
constexpr size_t NHWC_BF16_BYTES = NHWC_ELEMS * sizeof(unsigned short);

constexpr int CT = 64;    // channel tile
constexpr int PT = 128;   // pixel tile (60800 % 128 == 0)

__device__ __forceinline__ unsigned short f2bf_rne(float f) {
    unsigned int u = __float_as_uint(f);
    unsigned int r = (u + 0x7FFFu + ((u >> 16) & 1u)) >> 16;  // RNE
    return (unsigned short)r;
}

// ---------------- tiled transpose NCHW fp32 -> NHWC bf16 ----------------
// grid (PIX/PT = 475, N_IMG*CN/CT = 8), 256 threads.
// Phase 1: thread (q = t&31, r = t>>5) loads float4 of channel c = r + 8i
//   at pixel offset 4q. Per wave instruction (fixed i): 2 x 512-B bursts.
// Phase 2: thread (cq = t&7, p0 = t>>3) packs 8 channels -> uint4 at
//   pixel p = p0 + 32*i2; full-128B-line NHWC writes. Row stride 129
//   keeps phase-2 LDS reads at 2 lanes/bank (free).
__global__ __launch_bounds__(256) void nchw_to_nhwc_bf16_tiled(
    const float* __restrict__ in, unsigned short* __restrict__ ws)
{
    const int pbase = blockIdx.x * PT;
    const int nc = blockIdx.y;           // 0..7
    const int n = nc >> 2;
    const int cbase = (nc & 3) * CT;

    __shared__ float tile[CT][PT + 1];   // 64 x 129 fp32 = 33,024 B

    {
        const int q = threadIdx.x & 31;  // float4 slot within pixel row
        const int r = threadIdx.x >> 5;  // 0..7
        const float* src = in + ((size_t)n * CN + cbase) * PLANE + pbase + 4 * q;
#pragma unroll
        for (int i = 0; i < 8; ++i) {
            const int c = r + 8 * i;
            const float4 v = *(const float4*)(src + (size_t)c * PLANE);
            tile[c][4 * q + 0] = v.x;
            tile[c][4 * q + 1] = v.y;
            tile[c][4 * q + 2] = v.z;
            tile[c][4 * q + 3] = v.w;
        }
    }
    __syncthreads();
    {
        const int cq = threadIdx.x & 7;  // channel octet: channels 8cq..8cq+7
        const int p0 = threadIdx.x >> 3; // 0..31
        unsigned short* dstbase =
            ws + ((size_t)n * PLANE + pbase) * CN + cbase + 8 * cq;
#pragma unroll
        for (int i2 = 0; i2 < 4; ++i2) {
            const int p = p0 + 32 * i2;
            uint4 pk;
            pk.x = (unsigned int)f2bf_rne(tile[8 * cq + 0][p]) |
                   ((unsigned int)f2bf_rne(tile[8 * cq + 1][p]) << 16);
            pk.y = (unsigned int)f2bf_rne(tile[8 * cq + 2][p]) |
                   ((unsigned int)f2bf_rne(tile[8 * cq + 3][p]) << 16);
            pk.z = (unsigned int)f2bf_rne(tile[8 * cq + 4][p]) |
                   ((unsigned int)f2bf_rne(tile[8 * cq + 5][p]) << 16);
            pk.w = (unsigned int)f2bf_rne(tile[8 * cq + 6][p]) |
                   ((unsigned int)f2bf_rne(tile[8 * cq + 7][p]) << 16);
            *(uint4*)(dstbase + (size_t)p * CN) = pk;
        }
    }
}

// ---------------- gather on NHWC bf16: (roi, ph) blocks, XCD-swizzled ----
// 1-D grid of 3584; decode so all 7 ph of a roi share (id % 8) => same XCD.
// One wave (64 threads); thread t owns channels 4t..4t+3; each corner load
// is one uint2 -> the wave covers all 256 channels (512 B) per instruction.
__global__ __launch_bounds__(64) void roi_align_nhwc_bf16(
    const unsigned short* __restrict__ ws,
    const float* __restrict__ rois,
    float* __restrict__ out)
{
    const int b = blockIdx.x;
    const int x = b & 7;                 // XCD residue
    const int s_id = b >> 3;             // 0..447
    const int r  = (s_id / 7) * 8 + x;   // roi
    const int ph = s_id % 7;             // output row
    const int t  = threadIdx.x;          // channel quad: 4t..4t+3

    __shared__ float s_roi[5];
    __shared__ int   s_off[28][4];       // BYTE offsets into NHWC bf16 image
    __shared__ float s_w[28][4];
    __shared__ int   s_b;

    if (t < 5) s_roi[t] = rois[r * 5 + t];
    __syncthreads();

    if (t < 28) {
        const int s  = t;
        const int gy = s / 14;
        const int ix = s % 14;
        const float x1 = s_roi[1] * SPATIAL_SCALE - 0.5f;
        const float y1 = s_roi[2] * SPATIAL_SCALE - 0.5f;
        const float x2 = s_roi[3] * SPATIAL_SCALE - 0.5f;
        const float y2 = s_roi[4] * SPATIAL_SCALE - 0.5f;
        const float bin_w = (x2 - x1) / OUT_W;
        const float bin_h = (y2 - y1) / OUT_H;
        const float y = y1 + ph * bin_h + (gy + 0.5f) * bin_h * 0.5f;
        const float xf = x1 + (ix >> 1) * bin_w + ((ix & 1) + 0.5f) * bin_w * 0.5f;
        const float validf =
            (y > -1.0f && y < (float)FH && xf > -1.0f && xf < (float)FW) ? 1.0f : 0.0f;
        const float yc = fminf(fmaxf(y, 0.0f), (float)(FH - 1));
        const float xc = fminf(fmaxf(xf, 0.0f), (float)(FW - 1));
        const int y0 = (int)floorf(yc);
        const int x0 = (int)floorf(xc);
        const int y1i = min(y0 + 1, FH - 1);
        const int x1i = min(x0 + 1, FW - 1);
        const float ly = yc - (float)y0;
        const float lx = xc - (float)x0;
        const float hy = 1.0f - ly;
        const float hx = 1.0f - lx;
        s_off[s][0] = ((y0  * FW + x0 ) * CN) * 2;
        s_off[s][1] = ((y0  * FW + x1i) * CN) * 2;
        s_off[s][2] = ((y1i * FW + x0 ) * CN) * 2;
        s_off[s][3] = ((y1i * FW + x1i) * CN) * 2;
        s_w[s][0] = hy * hx * validf;
        s_w[s][1] = hy * lx * validf;
        s_w[s][2] = ly * hx * validf;
        s_w[s][3] = ly * lx * validf;
    }
    if (t == 0) s_b = (int)s_roi[0];
    __syncthreads();

    const char* base =
        (const char*)(ws + (size_t)s_b * (PLANE * CN)) + 8 * t;

    float acc0[OUT_W] = {0.f, 0.f, 0.f, 0.f, 0.f, 0.f, 0.f};
    float acc1[OUT_W] = {0.f, 0.f, 0.f, 0.f, 0.f, 0.f, 0.f};
    float acc2[OUT_W] = {0.f, 0.f, 0.f, 0.f, 0.f, 0.f, 0.f};
    float acc3[OUT_W] = {0.f, 0.f, 0.f, 0.f, 0.f, 0.f, 0.f};
#pragma unroll
    for (int s = 0; s < 28; ++s) {
        const int pw = (s % 14) >> 1;
#pragma unroll
        for (int k = 0; k < 4; ++k) {
            const uint2 u = *(const uint2*)(base + s_off[s][k]);
            const float f0 = __uint_as_float(u.x << 16);
            const float f1 = __uint_as_float(u.x & 0xFFFF0000u);
            const float f2 = __uint_as_float(u.y << 16);
            const float f3 = __uint_as_float(u.y & 0xFFFF0000u);
            const float w = s_w[s][k];
            acc0[pw] = fmaf(w, f0, acc0[pw]);
            acc1[pw] = fmaf(w, f1, acc1[pw]);
            acc2[pw] = fmaf(w, f2, acc2[pw]);
            acc3[pw] = fmaf(w, f3, acc3[pw]);
        }
    }

    const size_t outbase = ((size_t)r * CN + 4 * t) * (OUT_H * OUT_W) + (size_t)ph * OUT_W;
#pragma unroll
    for (int pw = 0; pw < OUT_W; ++pw) {
        out[outbase + 0 * (OUT_H * OUT_W) + pw] = acc0[pw] * 0.25f;
        out[outbase + 1 * (OUT_H * OUT_W) + pw] = acc1[pw] * 0.25f;
        out[outbase + 2 * (OUT_H * OUT_W) + pw] = acc2[pw] * 0.25f;
        out[outbase + 3 * (OUT_H * OUT_W) + pw] = acc3[pw] * 0.25f;
    }
}

// ---------------- fallback: NCHW gather (round-1 kernel) ----------------
__global__ __launch_bounds__(256) void roi_align_nchw(
    const float* __restrict__ feat,
    const float* __restrict__ rois,
    float* __restrict__ out)
{
    const int r  = blockIdx.x;
    const int ph = blockIdx.y;
    const int c  = threadIdx.x;

    __shared__ float s_roi[5];
    __shared__ int   s_off[28][4];
    __shared__ float s_w[28][4];
    __shared__ int   s_b;

    if (threadIdx.x < 5) s_roi[threadIdx.x] = rois[r * 5 + threadIdx.x];
    __syncthreads();

    if (threadIdx.x < 28) {
        const int s  = threadIdx.x;
        const int gy = s / 14;
        const int ix = s % 14;
        const float x1 = s_roi[1] * SPATIAL_SCALE - 0.5f;
        const float y1 = s_roi[2] * SPATIAL_SCALE - 0.5f;
        const float x2 = s_roi[3] * SPATIAL_SCALE - 0.5f;
        const float y2 = s_roi[4] * SPATIAL_SCALE - 0.5f;
        const float bin_w = (x2 - x1) / OUT_W;
        const float bin_h = (y2 - y1) / OUT_H;
        const float y = y1 + ph * bin_h + (gy + 0.5f) * bin_h * 0.5f;
        const float xf = x1 + (ix >> 1) * bin_w + ((ix & 1) + 0.5f) * bin_w * 0.5f;
        const float validf =
            (y > -1.0f && y < (float)FH && xf > -1.0f && xf < (float)FW) ? 1.0f : 0.0f;
        const float yc = fminf(fmaxf(y, 0.0f), (float)(FH - 1));
        const float xc = fminf(fmaxf(xf, 0.0f), (float)(FW - 1));
        const int y0 = (int)floorf(yc);
        const int x0 = (int)floorf(xc);
        const int y1i = min(y0 + 1, FH - 1);
        const int x1i = min(x0 + 1, FW - 1);
        const float ly = yc - (float)y0;
        const float lx = xc - (float)x0;
        const float hy = 1.0f - ly;
        const float hx = 1.0f - lx;
        s_off[s][0] = y0  * FW + x0;
        s_off[s][1] = y0  * FW + x1i;
        s_off[s][2] = y1i * FW + x0;
        s_off[s][3] = y1i * FW + x1i;
        s_w[s][0] = hy * hx * validf;
        s_w[s][1] = hy * lx * validf;
        s_w[s][2] = ly * hx * validf;
        s_w[s][3] = ly * lx * validf;
    }
    if (threadIdx.x == 0) s_b = (int)s_roi[0];
    __syncthreads();

    const float* base = feat + ((size_t)s_b * CN + c) * PLANE;

    float acc[OUT_W] = {0.f, 0.f, 0.f, 0.f, 0.f, 0.f, 0.f};
#pragma unroll
    for (int s = 0; s < 28; ++s) {
        const float v0 = base[s_off[s][0]];
        const float v1 = base[s_off[s][1]];
        const float v2 = base[s_off[s][2]];
        const float v3 = base[s_off[s][3]];
        acc[(s % 14) >> 1] += s_w[s][0] * v0 + s_w[s][1] * v1 +
                              s_w[s][2] * v2 + s_w[s][3] * v3;
    }

    const size_t outbase = ((size_t)r * CN + c) * (OUT_H * OUT_W) + (size_t)ph * OUT_W;
#pragma unroll
    for (int pw = 0; pw < OUT_W; ++pw) {
        out[outbase + pw] = acc[pw] * 0.25f;
    }
}

extern "C" void kernel_launch(void* const* d_in, const int* in_sizes, int n_in,
                              void* d_out, int out_size, void* d_ws, size_t ws_size,
                              hipStream_t stream) {
    const float* feat = (const float*)d_in[0];
    const float* rois = (const float*)d_in[1];
    float* out = (float*)d_out;

    if (ws_size >= NHWC_BF16_BYTES) {
        unsigned short* ws = (unsigned short*)d_ws;
        dim3 tgrid(PIX / PT, (N_IMG * CN) / CT, 1);  // 475 x 8 = 3800 blocks
        nchw_to_nhwc_bf16_tiled<<<tgrid, dim3(256, 1, 1), 0, stream>>>(feat, ws);
        roi_align_nhwc_bf16<<<dim3(N_ROIS * OUT_H, 1, 1), dim3(64, 1, 1), 0, stream>>>(
            ws, rois, out);
    } else {
        dim3 grid(N_ROIS, OUT_H, 1);
        roi_align_nchw<<<grid, dim3(256, 1, 1), 0, stream>>>(feat, rois, out);
    }
}